// Round 11
// baseline (304.050 us; speedup 1.0000x reference)
//
#include <hip/hip_runtime.h>
#include <stdint.h>

#define BATCH 8
#define LSEQ 16384
#define HDIM 128
#define KSZ 65
#define PADW 32
#define LH (LSEQ*HDIM)
#define TL 256
#define NROWS (TL + 2*PADW)     // 320 staged Q rows
#define LBLKS (LSEQ/TL)         // 64
#define EXP_SHIFT 20.0f
#define HSLOT 8192              // elems per half-tap slot (16 KB)
#define NPH (2*KSZ)             // 130 half-tap phases

#define WS_WBF_OFF 4096         // bf16 W half-tap slots start here; gsum f32[1024] at offset 0

typedef __attribute__((ext_vector_type(8))) short bf16x8;
typedef __attribute__((ext_vector_type(4))) short bf16x4;
typedef __attribute__((ext_vector_type(16))) float f32x16;

__device__ __forceinline__ unsigned short f2bf(float f) {
  unsigned int u = __float_as_uint(f);
  return (unsigned short)((u + 0x7FFFu + ((u >> 16) & 1u)) >> 16);  // RNE
}

// ---------------- K0: W [o][i][k] f32 -> half-tap fragment-ordered bf16 ----------------
// Wbf[p=(k,hk)][kq][ob][hi2][l31][e] : half-tap p is one contiguous 16 KB slot laid out
// exactly as the LDS slot (global_load_lds stages it linearly).
// o = ob*32 + l31 ; i = hk*64 + kq*16 + hi2*8 + e.
__global__ __launch_bounds__(256) void wcvt_kernel(const float* __restrict__ W,
                                                   unsigned short* __restrict__ Wbf) {
  __shared__ float lw[KSZ*HDIM];
  const int o = blockIdx.x;
  const float* src = W + (size_t)o * (HDIM*KSZ);
  for (int t = threadIdx.x; t < HDIM*KSZ; t += 256) lw[t] = src[t];
  __syncthreads();
  const int ob  = o >> 5;
  const int l31 = o & 31;
  for (int idx = threadIdx.x; idx < KSZ*HDIM; idx += 256) {
    const int k = idx >> 7;      // 0..64
    const int i = idx & 127;
    const int hk  = i >> 6;
    const int kq  = (i >> 4) & 3;
    const int hi2 = (i >> 3) & 1;
    const int e   = i & 7;
    const size_t dst = (size_t)(k*2 + hk)*HSLOT + kq*2048 + ob*512 + hi2*256 + l31*8 + e;
    Wbf[dst] = f2bf(lw[i*KSZ + k]);
  }
}

// stage one 16KB half-tap linearly into an LDS ring slot (8 waves x 2 x 1KB)
__device__ __forceinline__ void stage_half(const unsigned short* __restrict__ gsrc,
                                           char* lbase, int w, int lane) {
  const char* gb = (const char*)gsrc;
#pragma unroll
  for (int r = 0; r < 2; ++r) {
    const int off = r*8192 + w*1024;   // 8 waves * 64 lanes * 16B = 8192B per round
    __builtin_amdgcn_global_load_lds(
        (const __attribute__((address_space(1))) unsigned int*)(gb + off + lane*16),
        (__attribute__((address_space(3))) unsigned int*)(lbase + off),
        16, 0, 0);
  }
}

// ---------------- K1: conv GEMM, r5 geometry + 3-slot ring + counted vmcnt (T3+T4) ----------------
__global__ __launch_bounds__(512, 2) void conv_gate_kernel(
    const float* __restrict__ Qm, const float* __restrict__ Km,
    const unsigned short* __restrict__ Wfrag,
    float* __restrict__ Eout, float* __restrict__ gsum) {

  __shared__ __align__(16) char smem[131072];   // Qs 80K | W ring 3x16K ; reused as f32 red[]
  unsigned short* Qs = (unsigned short*)smem;
  char* WsBase = smem + 81920;

  const int tid  = threadIdx.x;
  const int lane = tid & 63;
  const int w    = tid >> 6;       // 0..7
  const int ks   = w & 1;          // i-band within each half-tap: [hk*64+ks*32, +32)
  const int wc   = (w >> 1) & 1;   // 0..1 : 64-col band
  const int wr   = w >> 2;         // 0..1 : 128-row band
  const int l31  = lane & 31;
  const int hi2  = lane >> 5;      // 0..1

  const int bx = blockIdx.x;
  const int b  = bx >> 6;
  const int l0 = (bx & 63) << 8;   // * TL

  // prologue: stage half-taps 0,1 into ring slots 0,1 (overlaps Q staging below)
  stage_half(Wfrag,         WsBase,         w, lane);
  stage_half(Wfrag + HSLOT, WsBase + 16384, w, lane);

  // ---- stage Q rows [l0-32, l0+TL+32) as swizzled bf16 ----
  {
    const int r0 = tid >> 5;            // 0..15
    const int c4 = (tid & 31) << 2;     // 0..124 step 4
    const float* qbase = Qm + (size_t)b*LH + c4;
#pragma unroll
    for (int it = 0; it < NROWS/16; ++it) {
      const int r = it*16 + r0;
      const int grow = l0 - PADW + r;
      bf16x4 pk = {0, 0, 0, 0};
      if (grow >= 0 && grow < LSEQ) {
        const float4 qv = *(const float4*)(qbase + (size_t)grow*HDIM);
        pk[0] = (short)f2bf(qv.x); pk[1] = (short)f2bf(qv.y);
        pk[2] = (short)f2bf(qv.z); pk[3] = (short)f2bf(qv.w);
      }
      *(bf16x4*)(&Qs[r*HDIM + (c4 ^ ((r & 15) << 3))]) = pk;
    }
  }

  f32x16 acc[4][2] = {};

  __syncthreads();   // Q staged + slots 0,1 landed (full drain once)

  const int arow0 = wr*128 + l31;
  const int bB = wc*1024 + hi2*256 + l31*8;     // + nf*512 + kq*2048, kq = ks*2 + c

#define LOADC(c, A, B) { \
    const int i0 = (hk*64 + ks*32 + (c)*16 + hi2*8) ^ xa; \
    A[0] = *(const bf16x8*)(&Qs[(rb     )*HDIM + i0]); \
    A[1] = *(const bf16x8*)(&Qs[(rb + 32)*HDIM + i0]); \
    A[2] = *(const bf16x8*)(&Qs[(rb + 64)*HDIM + i0]); \
    A[3] = *(const bf16x8*)(&Qs[(rb + 96)*HDIM + i0]); \
    B[0] = *(const bf16x8*)(&slot[(ks*2 + (c))*2048 + bB]); \
    B[1] = *(const bf16x8*)(&slot[(ks*2 + (c))*2048 + bB + 512]); \
  }
#define MM(A, B) \
    acc[0][0] = __builtin_amdgcn_mfma_f32_32x32x16_bf16(A[0], B[0], acc[0][0], 0, 0, 0); \
    acc[0][1] = __builtin_amdgcn_mfma_f32_32x32x16_bf16(A[0], B[1], acc[0][1], 0, 0, 0); \
    acc[1][0] = __builtin_amdgcn_mfma_f32_32x32x16_bf16(A[1], B[0], acc[1][0], 0, 0, 0); \
    acc[1][1] = __builtin_amdgcn_mfma_f32_32x32x16_bf16(A[1], B[1], acc[1][1], 0, 0, 0); \
    acc[2][0] = __builtin_amdgcn_mfma_f32_32x32x16_bf16(A[2], B[0], acc[2][0], 0, 0, 0); \
    acc[2][1] = __builtin_amdgcn_mfma_f32_32x32x16_bf16(A[2], B[1], acc[2][1], 0, 0, 0); \
    acc[3][0] = __builtin_amdgcn_mfma_f32_32x32x16_bf16(A[3], B[0], acc[3][0], 0, 0, 0); \
    acc[3][1] = __builtin_amdgcn_mfma_f32_32x32x16_bf16(A[3], B[1], acc[3][1], 0, 0, 0);

  int scur = 0;                                  // ring slot being read (= p % 3)
  const unsigned short* gstage = Wfrag + 2*HSLOT;  // next half-tap to stage

  for (int p = 0; p < NPH; ++p) {
    const int k  = p >> 1;
    const int hk = p & 1;
    const unsigned short* slot = (const unsigned short*)(WsBase + scur*16384);
    const int rb = k + arow0;          // sliding window: tap k shifts A rows by one
    const int xa = (rb & 15) << 3;     // rows rb,+32,+64,+96 share (r&15)

    bf16x8 A0[4], B0[2], A1[4], B1[2];
    LOADC(0, A0, B0)                   // 12 ds_read_b128 for THIS phase's MFMAs
    LOADC(1, A1, B1)

    if (p + 2 < NPH) {                 // stage slot p+2 (2 gload_lds/wave, ride across barriers)
      const int snxt = (scur == 0) ? 2 : scur - 1;   // (p+2) % 3
      stage_half(gstage, WsBase + snxt*16384, w, lane);
      gstage += HSLOT;
    }

    __builtin_amdgcn_sched_barrier(0);            // keep reads+stage above the barrier
    __builtin_amdgcn_s_barrier();
    asm volatile("s_waitcnt lgkmcnt(0)" ::: "memory");
    __builtin_amdgcn_sched_barrier(0);            // rule #18: MFMA stays below the wait
    __builtin_amdgcn_s_setprio(1);
    MM(A0, B0)
    MM(A1, B1)
    __builtin_amdgcn_s_setprio(0);
    // T4 counted wait: retire phase p-1's stage loads (slot p+1 publishable),
    // allow THIS phase's 2 loads to stay in flight. Close ring at the tail.
    if (p < NPH - 2) asm volatile("s_waitcnt vmcnt(2)" ::: "memory");
    else             asm volatile("s_waitcnt vmcnt(0)" ::: "memory");
    __builtin_amdgcn_s_barrier();                 // publish slot p+1
    scur = (scur == 2) ? 0 : scur + 1;
  }
#undef LOADC
#undef MM

  // ---- K-split reduction: ks=1 partial -> LDS -> ks=0 adds ----
  float* red = (float*)smem;                 // 4 regions x 32 KB, reuse Qs+ring
  const int widx = wr*2 + wc;
  float* reg = red + widx*8192 + lane*4;
  if (ks == 1) {
#pragma unroll
    for (int e4 = 0; e4 < 32; ++e4) {
      const int mfr = e4 >> 3, nf = (e4 >> 2) & 1, r4 = (e4 & 3) << 2;
      float4 v;
      v.x = acc[mfr][nf][r4];   v.y = acc[mfr][nf][r4+1];
      v.z = acc[mfr][nf][r4+2]; v.w = acc[mfr][nf][r4+3];
      *(float4*)(reg + e4*256) = v;
    }
  }
  __syncthreads();

  if (ks == 0) {
#pragma unroll
    for (int e4 = 0; e4 < 32; ++e4) {
      const int mfr = e4 >> 3, nf = (e4 >> 2) & 1, r4 = (e4 & 3) << 2;
      const float4 v = *(const float4*)(reg + e4*256);
      acc[mfr][nf][r4]   += v.x; acc[mfr][nf][r4+1] += v.y;
      acc[mfr][nf][r4+2] += v.z; acc[mfr][nf][r4+3] += v.w;
    }
    // ---- epilogue: gate by K, exp-shift, store E, per-column partial sums ----
    float psum[2] = {0.f, 0.f};
#pragma unroll
    for (int mfr = 0; mfr < 4; ++mfr) {
#pragma unroll
      for (int r = 0; r < 16; ++r) {
        const int row = wr*128 + mfr*32 + (r & 3) + 8*(r >> 2) + 4*hi2;  // C/D (m74/m101)
        const size_t gb = (size_t)b*LH + (size_t)(l0 + row)*HDIM + wc*64 + l31;
#pragma unroll
        for (int nf = 0; nf < 2; ++nf) {                                 // col = lane&31
          const float s = acc[mfr][nf][r] * Km[gb + nf*32];
          const float e = __expf(s - EXP_SHIFT);
          Eout[gb + nf*32] = e;
          psum[nf] += e;
        }
      }
    }
    psum[0] += __shfl_xor(psum[0], 32);   // fold hi2 halves (same column)
    psum[1] += __shfl_xor(psum[1], 32);
    if (hi2 == 0) {
      atomicAdd(&gsum[b*HDIM + wc*64 + l31],      psum[0]);
      atomicAdd(&gsum[b*HDIM + wc*64 + 32 + l31], psum[1]);
    }
  }
}

// ---------------- K2: Z = E * V / gsum (in place on d_out) ----------------
__global__ __launch_bounds__(256) void finalize_kernel(float* __restrict__ out,
                                                       const float* __restrict__ V,
                                                       const float* __restrict__ gsum) {
  const int total4 = (BATCH*LH) >> 2;
  const int stride = gridDim.x * blockDim.x;
  for (int f = blockIdx.x*blockDim.x + threadIdx.x; f < total4; f += stride) {
    const float4 e = ((const float4*)out)[f];
    const float4 v = ((const float4*)V)[f];
    const int e0 = f << 2;
    const float* gs = gsum + ((e0 >> 21) << 7) + (e0 & 127);   // b*128 + h0
    float4 z;
    z.x = e.x * v.x / gs[0];
    z.y = e.y * v.y / gs[1];
    z.z = e.z * v.z / gs[2];
    z.w = e.w * v.w / gs[3];
    ((float4*)out)[f] = z;
  }
}

extern "C" void kernel_launch(void* const* d_in, const int* in_sizes, int n_in,
                              void* d_out, int out_size, void* d_ws, size_t ws_size,
                              hipStream_t stream) {
  (void)in_sizes; (void)n_in; (void)out_size; (void)ws_size;
  const float* Q = (const float*)d_in[0];
  const float* K = (const float*)d_in[1];
  const float* V = (const float*)d_in[2];
  const float* W = (const float*)d_in[3];
  float* out  = (float*)d_out;
  float* gsum = (float*)d_ws;
  unsigned short* Wbf = (unsigned short*)((char*)d_ws + WS_WBF_OFF);

  hipMemsetAsync(d_ws, 0, BATCH*HDIM*sizeof(float), stream);          // gsum = 0
  wcvt_kernel<<<HDIM, 256, 0, stream>>>(W, Wbf);                      // W -> half-tap frag order
  conv_gate_kernel<<<BATCH*LBLKS, 512, 0, stream>>>(Q, K, Wbf, out, gsum);
  finalize_kernel<<<2048, 256, 0, stream>>>(out, V, gsum);
}